// Round 1
// baseline (346.920 us; speedup 1.0000x reference)
//
#include <hip/hip_runtime.h>
#include <hip/hip_bf16.h>
#include <math.h>

// Shapes (fixed by the problem)
#define BB 2
#define TT 2048
#define DD 512
#define HH 8
#define HD 64
#define FF_ 2048
#define M4 4096  // BB*TT

typedef __attribute__((ext_vector_type(8))) __bf16 bf16x8;
typedef __attribute__((ext_vector_type(4))) float floatx4;

__device__ __forceinline__ unsigned short f2bf(float f) {
  unsigned u = __builtin_bit_cast(unsigned, f);
  u += 0x7fffu + ((u >> 16) & 1u);  // RNE
  return (unsigned short)(u >> 16);
}

__device__ __forceinline__ bf16x8 frag16(const unsigned short* p) {
  return __builtin_bit_cast(bf16x8, *(const uint4*)p);
}

__device__ __forceinline__ floatx4 mfma_bf16(bf16x8 a, bf16x8 b, floatx4 c) {
  return __builtin_amdgcn_mfma_f32_16x16x32_bf16(a, b, c, 0, 0, 0);
}

// ---------------- weight transpose + bf16 convert: src (K,N) f32 -> dst (N,K) bf16
__global__ void transpose_bf16(const float* __restrict__ src, unsigned short* __restrict__ dst,
                               int K, int N) {
  __shared__ float tile[32][33];
  int n0 = blockIdx.x * 32, k0 = blockIdx.y * 32;
  for (int i = threadIdx.y; i < 32; i += 8)
    tile[i][threadIdx.x] = src[(size_t)(k0 + i) * N + n0 + threadIdx.x];
  __syncthreads();
  for (int i = threadIdx.y; i < 32; i += 8)
    dst[(size_t)(n0 + i) * K + k0 + threadIdx.x] = f2bf(tile[threadIdx.x][i]);
}

// ---------------- LayerNorm: fp32 (rows of 512) -> bf16
__global__ __launch_bounds__(128) void ln_kernel(const float* __restrict__ src,
                                                 const float* __restrict__ gg,
                                                 const float* __restrict__ bb,
                                                 unsigned short* __restrict__ dst) {
  const int row = blockIdx.x;
  const int t = threadIdx.x;
  float4 v = ((const float4*)(src + (size_t)row * DD))[t];
  float s = v.x + v.y + v.z + v.w;
  float ss = v.x * v.x + v.y * v.y + v.z * v.z + v.w * v.w;
#pragma unroll
  for (int o = 32; o >= 1; o >>= 1) {
    s += __shfl_xor(s, o);
    ss += __shfl_xor(ss, o);
  }
  __shared__ float ls[2], lss[2];
  if ((t & 63) == 0) { ls[t >> 6] = s; lss[t >> 6] = ss; }
  __syncthreads();
  float S = ls[0] + ls[1];
  float SS = lss[0] + lss[1];
  float mean = S * (1.f / DD);
  float var = SS * (1.f / DD) - mean * mean;
  float rstd = rsqrtf(var + 1e-5f);
  int c = t * 4;
  ushort4 o4;
  o4.x = f2bf((v.x - mean) * rstd * gg[c + 0] + bb[c + 0]);
  o4.y = f2bf((v.y - mean) * rstd * gg[c + 1] + bb[c + 1]);
  o4.z = f2bf((v.z - mean) * rstd * gg[c + 2] + bb[c + 2]);
  o4.w = f2bf((v.w - mean) * rstd * gg[c + 3] + bb[c + 3]);
  ((ushort4*)(dst + (size_t)row * DD))[t] = o4;
}

// ---------------- generic bf16 GEMM: C(M,N) = A(M,K) * Bt(N,K)^T, fused epilogues
// EPI 0: QKV (elu+1 for Q/K, pad-mask K/V, V stored transposed per-head)
// EPI 1: fp32 out = acc + bias[col] + residual[row,col]
// EPI 2: bf16 out = gelu(acc + bias[col])
template <int BM, int BN, int EPI>
__global__ __launch_bounds__(256) void gemm_bt(
    const unsigned short* __restrict__ A, const unsigned short* __restrict__ Bt,
    int N, int K,
    const float* __restrict__ e0, const float* __restrict__ e1,
    float* __restrict__ o0, unsigned short* __restrict__ ob,
    unsigned short* __restrict__ okk, unsigned short* __restrict__ ov,
    const unsigned char* __restrict__ msk) {
  constexpr int FM = BM / 32;
  constexpr int FN = BN / 32;
  __shared__ __align__(16) unsigned short As[BM * 40];  // +8 pad: 2-way LDS aliasing (free)
  __shared__ __align__(16) unsigned short Bs[BN * 40];

  const int tid = threadIdx.x;
  const int wid = tid >> 6;
  const int lane = tid & 63;
  const int ln = lane & 15;
  const int quad = lane >> 4;
  const int wm = (wid >> 1) * (BM / 2);
  const int wn = (wid & 1) * (BN / 2);
  const int m0 = blockIdx.y * BM;
  const int n0 = blockIdx.x * BN;

  floatx4 acc[FM][FN];
#pragma unroll
  for (int i = 0; i < FM; ++i)
#pragma unroll
    for (int j = 0; j < FN; ++j) acc[i][j] = (floatx4){0.f, 0.f, 0.f, 0.f};

  for (int k0 = 0; k0 < K; k0 += 32) {
    uint4 ga[BM / 64], gb[BN / 64];
#pragma unroll
    for (int r = 0; r < BM / 64; ++r) {
      int c = tid + r * 256;
      ga[r] = *(const uint4*)(A + (size_t)(m0 + (c >> 2)) * K + k0 + (c & 3) * 8);
    }
#pragma unroll
    for (int r = 0; r < BN / 64; ++r) {
      int c = tid + r * 256;
      gb[r] = *(const uint4*)(Bt + (size_t)(n0 + (c >> 2)) * K + k0 + (c & 3) * 8);
    }
    __syncthreads();  // previous iter's frag reads done
#pragma unroll
    for (int r = 0; r < BM / 64; ++r) {
      int c = tid + r * 256;
      *(uint4*)(&As[(c >> 2) * 40 + (c & 3) * 8]) = ga[r];
    }
#pragma unroll
    for (int r = 0; r < BN / 64; ++r) {
      int c = tid + r * 256;
      *(uint4*)(&Bs[(c >> 2) * 40 + (c & 3) * 8]) = gb[r];
    }
    __syncthreads();

    bf16x8 af[FM], bfr[FN];
#pragma unroll
    for (int mb = 0; mb < FM; ++mb)
      af[mb] = frag16(&As[(wm + mb * 16 + ln) * 40 + quad * 8]);
#pragma unroll
    for (int nb = 0; nb < FN; ++nb)
      bfr[nb] = frag16(&Bs[(wn + nb * 16 + ln) * 40 + quad * 8]);
#pragma unroll
    for (int mb = 0; mb < FM; ++mb)
#pragma unroll
      for (int nb = 0; nb < FN; ++nb)
        acc[mb][nb] = mfma_bf16(af[mb], bfr[nb], acc[mb][nb]);
  }

#pragma unroll
  for (int mb = 0; mb < FM; ++mb)
#pragma unroll
    for (int nb = 0; nb < FN; ++nb)
#pragma unroll
      for (int r = 0; r < 4; ++r) {
        int row = m0 + wm + mb * 16 + quad * 4 + r;  // C/D: row = quad*4+reg
        int col = n0 + wn + nb * 16 + ln;            //       col = lane&15
        float v = acc[mb][nb][r];
        if constexpr (EPI == 0) {
          int bq = row >> 11, t = row & 2047;
          float padv = msk[(bq << 11) + t] ? 0.f : 1.f;
          if (col < 512) {  // Q = elu(z)+1
            int h = col >> 6, hd = col & 63;
            float q = v > 0.f ? v + 1.f : expf(v);
            ob[(((size_t)(bq * HH + h) * TT + t) << 6) + hd] = f2bf(q);
          } else if (col < 1024) {  // K = (elu(z)+1)*pad
            int c2 = col - 512, h = c2 >> 6, hd = c2 & 63;
            float kf = (v > 0.f ? v + 1.f : expf(v)) * padv;
            okk[(((size_t)(bq * HH + h) * TT + t) << 6) + hd] = f2bf(kf);
          } else {  // V*pad, stored transposed (B,H,HD,T)
            int c2 = col - 1024, h = c2 >> 6, hd = c2 & 63;
            ov[(((size_t)(bq * HH + h) * HD + hd) << 11) + t] = f2bf(v * padv);
          }
        } else if constexpr (EPI == 1) {
          size_t idx = (size_t)row * N + col;
          o0[idx] = v + e0[col] + e1[idx];
        } else {  // EPI == 2: exact gelu
          float z = v + e0[col];
          float g = 0.5f * z * (1.f + erff(z * 0.70710678118654752f));
          ob[(size_t)row * N + col] = f2bf(g);
        }
      }
}

// ---------------- decayed attention, flash-style; i-tile 64, j-tile 128
__global__ __launch_bounds__(256) void attn_kernel(
    const unsigned short* __restrict__ Qg, const unsigned short* __restrict__ Kg,
    const unsigned short* __restrict__ Vtg, const float* __restrict__ dlg,
    unsigned short* __restrict__ attn_out) {
  __shared__ __align__(16) unsigned short Ks[128 * 72];   // K-tile (j,hd), pad 64->72
  __shared__ __align__(16) unsigned short Vts[64 * 136];  // V^T tile (hd,j), pad 128->136
  __shared__ __align__(16) unsigned short Ss[64 * 136];   // S tile (i,j) roundtrip

  const int tid = threadIdx.x;
  const int wid = tid >> 6;
  const int lane = tid & 63;
  const int ln = lane & 15;
  const int quad = lane >> 4;

  const int i0 = blockIdx.x * 64;
  const int bh = blockIdx.y;
  const int b = bh >> 3, h = bh & 7;

  const unsigned short* Qb = Qg + (size_t)bh * TT * HD;
  const unsigned short* Kb = Kg + (size_t)bh * TT * HD;
  const unsigned short* Vb = Vtg + (size_t)bh * HD * TT;

  const float logit = dlg[h];
  const float dec = 1.f / (1.f + expf(-logit));
  const float l2d = log2f(fmaxf(dec, 1e-8f));
  const bool fast = (l2d >= -1.0f);  // factorized path safe (no fp32 overflow) for d>0.5

  // Q A-fragments (rows i0+wid*16+ln), kept in regs across the j-loop
  bf16x8 qa[2];
#pragma unroll
  for (int kb = 0; kb < 2; ++kb)
    qa[kb] = frag16(Qb + (size_t)(i0 + wid * 16 + ln) * HD + kb * 32 + quad * 8);

  // per-lane decay factor tables: d^(i-i0), d^-(i-i0), d^-(j-j0), d^(j-j0)
  float rf[4], rfi[4], cf[8], cfi[8];
#pragma unroll
  for (int r = 0; r < 4; ++r) {
    float il = (float)(wid * 16 + quad * 4 + r);
    rf[r] = exp2f(l2d * il);
    rfi[r] = exp2f(-l2d * il);
  }
#pragma unroll
  for (int nb = 0; nb < 8; ++nb) {
    float jl = (float)(nb * 16 + ln);
    cf[nb] = exp2f(-l2d * jl);
    cfi[nb] = exp2f(l2d * jl);
  }

  floatx4 oacc[4];
#pragma unroll
  for (int i = 0; i < 4; ++i) oacc[i] = (floatx4){0.f, 0.f, 0.f, 0.f};
  float zacc[4] = {0.f, 0.f, 0.f, 0.f};

  for (int j0 = 0; j0 < TT; j0 += 128) {
    const int gap = i0 - j0;
    int mind = 0;
    if (gap >= 128) mind = gap - 127;
    else if (gap <= -64) mind = -gap - 63;
    if (l2d * (float)mind < -40.f) continue;  // max tile weight < 2^-40: negligible

    __syncthreads();  // previous PV reads done before restaging
#pragma unroll
    for (int r2 = 0; r2 < 4; ++r2) {
      int c = tid + r2 * 256;
      int row = c >> 3, c16 = (c & 7) * 8;
      *(uint4*)(&Ks[row * 72 + c16]) = *(const uint4*)(Kb + (size_t)(j0 + row) * HD + c16);
    }
#pragma unroll
    for (int r2 = 0; r2 < 4; ++r2) {
      int c = tid + r2 * 256;
      int row = c >> 4, c16 = (c & 15) * 8;
      *(uint4*)(&Vts[row * 136 + c16]) = *(const uint4*)(Vb + (size_t)row * TT + j0 + c16);
    }
    __syncthreads();

    const float wS = exp2f(l2d * (float)gap);    // d^(i0-j0)   (used when i>=j)
    const float wSb = exp2f(-l2d * (float)gap);  // d^(j0-i0)   (used when j>i)

#pragma unroll
    for (int nb = 0; nb < 8; ++nb) {
      floatx4 sacc = (floatx4){0.f, 0.f, 0.f, 0.f};
#pragma unroll
      for (int kb = 0; kb < 2; ++kb) {
        bf16x8 bk = frag16(&Ks[(nb * 16 + ln) * 72 + kb * 32 + quad * 8]);
        sacc = mfma_bf16(qa[kb], bk, sacc);
      }
#pragma unroll
      for (int r = 0; r < 4; ++r) {
        int il = wid * 16 + quad * 4 + r;
        int jl = nb * 16 + ln;
        int sd = gap + il - jl;  // i - j
        float w;
        if (fast)
          w = (sd >= 0) ? (wS * rf[r]) * cf[nb] : (wSb * rfi[r]) * cfi[nb];
        else
          w = exp2f(l2d * fabsf((float)sd));
        float sv = sacc[r] * w;
        zacc[r] += sv;
        Ss[(size_t)(wid * 16 + quad * 4 + r) * 136 + nb * 16 + ln] = f2bf(sv);
      }
    }
    __syncthreads();  // S visible (also orders within-wave write->read)

    bf16x8 af[4];
#pragma unroll
    for (int kb = 0; kb < 4; ++kb)
      af[kb] = frag16(&Ss[(size_t)(wid * 16 + ln) * 136 + kb * 32 + quad * 8]);
#pragma unroll
    for (int n2 = 0; n2 < 4; ++n2) {
#pragma unroll
      for (int kb = 0; kb < 4; ++kb) {
        bf16x8 bv = frag16(&Vts[(size_t)(n2 * 16 + ln) * 136 + kb * 32 + quad * 8]);
        oacc[n2] = mfma_bf16(af[kb], bv, oacc[n2]);
      }
    }
  }

  // row-sum denominator: reduce zacc across the 16 lanes of each quad
  float rz[4];
#pragma unroll
  for (int r = 0; r < 4; ++r) {
    float z = zacc[r];
    z += __shfl_xor(z, 1);
    z += __shfl_xor(z, 2);
    z += __shfl_xor(z, 4);
    z += __shfl_xor(z, 8);
    rz[r] = 1.f / fmaxf(z, 1e-6f);
  }

#pragma unroll
  for (int n2 = 0; n2 < 4; ++n2)
#pragma unroll
    for (int r = 0; r < 4; ++r) {
      int i = i0 + wid * 16 + quad * 4 + r;
      int col = h * 64 + n2 * 16 + ln;
      attn_out[(size_t)(b * TT + i) * DD + col] = f2bf(oacc[n2][r] * rz[r]);
    }
}

extern "C" void kernel_launch(void* const* d_in, const int* in_sizes, int n_in,
                              void* d_out, int out_size, void* d_ws, size_t ws_size,
                              hipStream_t stream) {
  const float* x = (const float*)d_in[0];
  const unsigned char* msk = (const unsigned char*)d_in[1];
  const float* wq = (const float*)d_in[2];
  const float* wk = (const float*)d_in[3];
  const float* wv = (const float*)d_in[4];
  const float* wo = (const float*)d_in[5];
  const float* bo = (const float*)d_in[6];
  const float* g1 = (const float*)d_in[7];
  const float* b1 = (const float*)d_in[8];
  const float* g2 = (const float*)d_in[9];
  const float* b2 = (const float*)d_in[10];
  const float* w1 = (const float*)d_in[11];
  const float* bf1 = (const float*)d_in[12];
  const float* w2 = (const float*)d_in[13];
  const float* bf2 = (const float*)d_in[14];
  const float* dlg = (const float*)d_in[15];
  float* out = (float*)d_out;

  char* p = (char*)d_ws;
  size_t off = 0;
  auto carve = [&](size_t bytes) {
    char* q = p + off;
    off += (bytes + 255) & ~(size_t)255;
    return q;
  };
  unsigned short* xn = (unsigned short*)carve((size_t)M4 * DD * 2);
  unsigned short* wqkvT = (unsigned short*)carve((size_t)1536 * DD * 2);
  unsigned short* woT = (unsigned short*)carve((size_t)DD * DD * 2);
  unsigned short* w1T = (unsigned short*)carve((size_t)FF_ * DD * 2);
  unsigned short* w2T = (unsigned short*)carve((size_t)DD * FF_ * 2);
  unsigned short* Qb = (unsigned short*)carve((size_t)16 * TT * HD * 2);
  unsigned short* Kb = (unsigned short*)carve((size_t)16 * TT * HD * 2);
  unsigned short* Vtb = (unsigned short*)carve((size_t)16 * HD * TT * 2);
  unsigned short* attn = (unsigned short*)carve((size_t)M4 * DD * 2);
  float* x2 = (float*)carve((size_t)M4 * DD * 4);
  unsigned short* xn2 = (unsigned short*)carve((size_t)M4 * DD * 2);
  unsigned short* ffh = (unsigned short*)carve((size_t)M4 * FF_ * 2);

  dim3 tb(32, 8);
  transpose_bf16<<<dim3(16, 16), tb, 0, stream>>>(wq, wqkvT, DD, DD);
  transpose_bf16<<<dim3(16, 16), tb, 0, stream>>>(wk, wqkvT + 512 * 512, DD, DD);
  transpose_bf16<<<dim3(16, 16), tb, 0, stream>>>(wv, wqkvT + 2 * 512 * 512, DD, DD);
  transpose_bf16<<<dim3(16, 16), tb, 0, stream>>>(wo, woT, DD, DD);
  transpose_bf16<<<dim3(64, 16), tb, 0, stream>>>(w1, w1T, DD, FF_);
  transpose_bf16<<<dim3(16, 64), tb, 0, stream>>>(w2, w2T, FF_, DD);

  ln_kernel<<<M4, 128, 0, stream>>>(x, g1, b1, xn);

  gemm_bt<128, 128, 0><<<dim3(1536 / 128, M4 / 128), 256, 0, stream>>>(
      xn, wqkvT, 1536, DD, nullptr, nullptr, nullptr, Qb, Kb, Vtb, msk);

  attn_kernel<<<dim3(TT / 64, 16), 256, 0, stream>>>(Qb, Kb, Vtb, dlg, attn);

  gemm_bt<64, 128, 1><<<dim3(DD / 128, M4 / 64), 256, 0, stream>>>(
      attn, woT, DD, DD, bo, x, x2, nullptr, nullptr, nullptr, nullptr);

  ln_kernel<<<M4, 128, 0, stream>>>(x2, g2, b2, xn2);

  gemm_bt<128, 128, 2><<<dim3(FF_ / 128, M4 / 128), 256, 0, stream>>>(
      xn2, w1T, FF_, DD, bf1, nullptr, nullptr, ffh, nullptr, nullptr, nullptr);

  gemm_bt<64, 128, 1><<<dim3(DD / 128, M4 / 64), 256, 0, stream>>>(
      ffh, w2T, DD, FF_, bf2, x2, out, nullptr, nullptr, nullptr, nullptr);
}

// Round 2
// 278.632 us; speedup vs baseline: 1.2451x; 1.2451x over previous
//
#include <hip/hip_runtime.h>
#include <hip/hip_bf16.h>
#include <math.h>

// Shapes (fixed by the problem)
#define BB 2
#define TT 2048
#define DD 512
#define HH 8
#define HD 64
#define FF_ 2048
#define M4 4096  // BB*TT

typedef __attribute__((ext_vector_type(8))) __bf16 bf16x8;
typedef __attribute__((ext_vector_type(4))) float floatx4;

__device__ __forceinline__ unsigned short f2bf(float f) {
  unsigned u = __builtin_bit_cast(unsigned, f);
  u += 0x7fffu + ((u >> 16) & 1u);  // RNE
  return (unsigned short)(u >> 16);
}

__device__ __forceinline__ bf16x8 frag16(const unsigned short* p) {
  return __builtin_bit_cast(bf16x8, *(const uint4*)p);
}

__device__ __forceinline__ floatx4 mfma_bf16(bf16x8 a, bf16x8 b, floatx4 c) {
  return __builtin_amdgcn_mfma_f32_16x16x32_bf16(a, b, c, 0, 0, 0);
}

// ---------------- weight transpose + bf16 convert: src (K,N) f32 -> dst (N,K) bf16
__global__ void transpose_bf16(const float* __restrict__ src, unsigned short* __restrict__ dst,
                               int K, int N) {
  __shared__ float tile[32][33];
  int n0 = blockIdx.x * 32, k0 = blockIdx.y * 32;
  for (int i = threadIdx.y; i < 32; i += 8)
    tile[i][threadIdx.x] = src[(size_t)(k0 + i) * N + n0 + threadIdx.x];
  __syncthreads();
  for (int i = threadIdx.y; i < 32; i += 8)
    dst[(size_t)(n0 + i) * K + k0 + threadIdx.x] = f2bf(tile[threadIdx.x][i]);
}

// ---------------- LayerNorm: fp32 (rows of 512) -> bf16
__global__ __launch_bounds__(128) void ln_kernel(const float* __restrict__ src,
                                                 const float* __restrict__ gg,
                                                 const float* __restrict__ bb,
                                                 unsigned short* __restrict__ dst) {
  const int row = blockIdx.x;
  const int t = threadIdx.x;
  float4 v = ((const float4*)(src + (size_t)row * DD))[t];
  float s = v.x + v.y + v.z + v.w;
  float ss = v.x * v.x + v.y * v.y + v.z * v.z + v.w * v.w;
#pragma unroll
  for (int o = 32; o >= 1; o >>= 1) {
    s += __shfl_xor(s, o);
    ss += __shfl_xor(ss, o);
  }
  __shared__ float ls[2], lss[2];
  if ((t & 63) == 0) { ls[t >> 6] = s; lss[t >> 6] = ss; }
  __syncthreads();
  float S = ls[0] + ls[1];
  float SS = lss[0] + lss[1];
  float mean = S * (1.f / DD);
  float var = SS * (1.f / DD) - mean * mean;
  float rstd = rsqrtf(var + 1e-5f);
  int c = t * 4;
  ushort4 o4;
  o4.x = f2bf((v.x - mean) * rstd * gg[c + 0] + bb[c + 0]);
  o4.y = f2bf((v.y - mean) * rstd * gg[c + 1] + bb[c + 1]);
  o4.z = f2bf((v.z - mean) * rstd * gg[c + 2] + bb[c + 2]);
  o4.w = f2bf((v.w - mean) * rstd * gg[c + 3] + bb[c + 3]);
  ((ushort4*)(dst + (size_t)row * DD))[t] = o4;
}

// ---------------- generic bf16 GEMM: C(M,N) = A(M,K) * Bt(N,K)^T, fused epilogues
// Software-pipelined: register prefetch (distance 1) + double-buffered LDS,
// ONE barrier per K-iter. Global-load latency overlaps MFMA of the previous tile.
// EPI 0: QKV (elu+1 for Q/K, pad-mask K/V, V stored transposed per-head)
// EPI 1: fp32 out = acc + bias[col] + residual[row,col]
// EPI 2: bf16 out = gelu(acc + bias[col])
template <int BM, int BN, int EPI>
__global__ __launch_bounds__(256) void gemm_bt(
    const unsigned short* __restrict__ A, const unsigned short* __restrict__ Bt,
    int N, int K,
    const float* __restrict__ e0, const float* __restrict__ e1,
    float* __restrict__ o0, unsigned short* __restrict__ ob,
    unsigned short* __restrict__ okk, unsigned short* __restrict__ ov,
    const unsigned char* __restrict__ msk) {
  constexpr int FM = BM / 32;
  constexpr int FN = BN / 32;
  constexpr int RA = BM / 64;  // uint4 staging loads per thread (A)
  constexpr int RB = BN / 64;
  __shared__ __align__(16) unsigned short As[2][BM * 40];  // +8 pad: 2-way aliasing (free, m136)
  __shared__ __align__(16) unsigned short Bs[2][BN * 40];

  const int tid = threadIdx.x;
  const int wid = tid >> 6;
  const int lane = tid & 63;
  const int ln = lane & 15;
  const int quad = lane >> 4;
  const int wm = (wid >> 1) * (BM / 2);
  const int wn = (wid & 1) * (BN / 2);
  const int m0 = blockIdx.y * BM;
  const int n0 = blockIdx.x * BN;

  const int srow = tid >> 2;           // staging row (0..63)
  const int scol = (tid & 3) * 8;      // staging col (halves)
  const unsigned short* Ag = A + (size_t)(m0 + srow) * K + scol;
  const unsigned short* Bg = Bt + (size_t)(n0 + srow) * K + scol;

  floatx4 acc[FM][FN];
#pragma unroll
  for (int i = 0; i < FM; ++i)
#pragma unroll
    for (int j = 0; j < FN; ++j) acc[i][j] = (floatx4){0.f, 0.f, 0.f, 0.f};

  uint4 ga[RA], gb[RB];
  // prologue: load + stage tile 0
#pragma unroll
  for (int r = 0; r < RA; ++r) ga[r] = *(const uint4*)(Ag + (size_t)(r * 64) * K);
#pragma unroll
  for (int r = 0; r < RB; ++r) gb[r] = *(const uint4*)(Bg + (size_t)(r * 64) * K);
#pragma unroll
  for (int r = 0; r < RA; ++r) *(uint4*)(&As[0][(srow + r * 64) * 40 + scol]) = ga[r];
#pragma unroll
  for (int r = 0; r < RB; ++r) *(uint4*)(&Bs[0][(srow + r * 64) * 40 + scol]) = gb[r];
  __syncthreads();

  const int nIter = K / 32;
  for (int it = 0; it < nIter; ++it) {
    const int cur = it & 1;
    const bool more = (it + 1 < nIter);
    if (more) {  // issue prefetch loads first: latency overlaps MFMA below
      const size_t ko = (size_t)(it + 1) * 32;
#pragma unroll
      for (int r = 0; r < RA; ++r) ga[r] = *(const uint4*)(Ag + (size_t)(r * 64) * K + ko);
#pragma unroll
      for (int r = 0; r < RB; ++r) gb[r] = *(const uint4*)(Bg + (size_t)(r * 64) * K + ko);
    }

    bf16x8 af[FM], bfr[FN];
#pragma unroll
    for (int mb = 0; mb < FM; ++mb)
      af[mb] = frag16(&As[cur][(wm + mb * 16 + ln) * 40 + quad * 8]);
#pragma unroll
    for (int nb = 0; nb < FN; ++nb)
      bfr[nb] = frag16(&Bs[cur][(wn + nb * 16 + ln) * 40 + quad * 8]);
#pragma unroll
    for (int mb = 0; mb < FM; ++mb)
#pragma unroll
      for (int nb = 0; nb < FN; ++nb)
        acc[mb][nb] = mfma_bf16(af[mb], bfr[nb], acc[mb][nb]);

    if (more) {  // drain vmcnt into the other buffer (write-after-read safe: barrier of it-1)
#pragma unroll
      for (int r = 0; r < RA; ++r) *(uint4*)(&As[cur ^ 1][(srow + r * 64) * 40 + scol]) = ga[r];
#pragma unroll
      for (int r = 0; r < RB; ++r) *(uint4*)(&Bs[cur ^ 1][(srow + r * 64) * 40 + scol]) = gb[r];
      __syncthreads();
    }
  }

#pragma unroll
  for (int mb = 0; mb < FM; ++mb)
#pragma unroll
    for (int nb = 0; nb < FN; ++nb)
#pragma unroll
      for (int r = 0; r < 4; ++r) {
        int row = m0 + wm + mb * 16 + quad * 4 + r;  // C/D: row = quad*4+reg
        int col = n0 + wn + nb * 16 + ln;            //       col = lane&15
        float v = acc[mb][nb][r];
        if constexpr (EPI == 0) {
          int bq = row >> 11, t = row & 2047;
          float padv = msk[(bq << 11) + t] ? 0.f : 1.f;
          if (col < 512) {  // Q = elu(z)+1
            int h = col >> 6, hd = col & 63;
            float q = v > 0.f ? v + 1.f : expf(v);
            ob[(((size_t)(bq * HH + h) * TT + t) << 6) + hd] = f2bf(q);
          } else if (col < 1024) {  // K = (elu(z)+1)*pad
            int c2 = col - 512, h = c2 >> 6, hd = c2 & 63;
            float kf = (v > 0.f ? v + 1.f : expf(v)) * padv;
            okk[(((size_t)(bq * HH + h) * TT + t) << 6) + hd] = f2bf(kf);
          } else {  // V*pad, stored transposed (B,H,HD,T)
            int c2 = col - 1024, h = c2 >> 6, hd = c2 & 63;
            ov[(((size_t)(bq * HH + h) * HD + hd) << 11) + t] = f2bf(v * padv);
          }
        } else if constexpr (EPI == 1) {
          size_t idx = (size_t)row * N + col;
          o0[idx] = v + e0[col] + e1[idx];
        } else {  // EPI == 2: exact gelu
          float z = v + e0[col];
          float g = 0.5f * z * (1.f + erff(z * 0.70710678118654752f));
          ob[(size_t)row * N + col] = f2bf(g);
        }
      }
}

// ---------------- decayed attention, flash-style; i-tile 64, j-tile 128
__global__ __launch_bounds__(256) void attn_kernel(
    const unsigned short* __restrict__ Qg, const unsigned short* __restrict__ Kg,
    const unsigned short* __restrict__ Vtg, const float* __restrict__ dlg,
    unsigned short* __restrict__ attn_out) {
  __shared__ __align__(16) unsigned short Ks[128 * 72];   // K-tile (j,hd), pad 64->72
  __shared__ __align__(16) unsigned short Vts[64 * 136];  // V^T tile (hd,j), pad 128->136
  __shared__ __align__(16) unsigned short Ss[64 * 136];   // S tile (i,j) roundtrip

  const int tid = threadIdx.x;
  const int wid = tid >> 6;
  const int lane = tid & 63;
  const int ln = lane & 15;
  const int quad = lane >> 4;

  const int i0 = blockIdx.x * 64;
  const int bh = blockIdx.y;
  const int b = bh >> 3, h = bh & 7;

  const unsigned short* Qb = Qg + (size_t)bh * TT * HD;
  const unsigned short* Kb = Kg + (size_t)bh * TT * HD;
  const unsigned short* Vb = Vtg + (size_t)bh * HD * TT;

  const float logit = dlg[h];
  const float dec = 1.f / (1.f + expf(-logit));
  const float l2d = log2f(fmaxf(dec, 1e-8f));
  const bool fast = (l2d >= -1.0f);  // factorized path safe (no fp32 overflow) for d>0.5

  // Q A-fragments (rows i0+wid*16+ln), kept in regs across the j-loop
  bf16x8 qa[2];
#pragma unroll
  for (int kb = 0; kb < 2; ++kb)
    qa[kb] = frag16(Qb + (size_t)(i0 + wid * 16 + ln) * HD + kb * 32 + quad * 8);

  // per-lane decay factor tables: d^(i-i0), d^-(i-i0), d^-(j-j0), d^(j-j0)
  float rf[4], rfi[4], cf[8], cfi[8];
#pragma unroll
  for (int r = 0; r < 4; ++r) {
    float il = (float)(wid * 16 + quad * 4 + r);
    rf[r] = exp2f(l2d * il);
    rfi[r] = exp2f(-l2d * il);
  }
#pragma unroll
  for (int nb = 0; nb < 8; ++nb) {
    float jl = (float)(nb * 16 + ln);
    cf[nb] = exp2f(-l2d * jl);
    cfi[nb] = exp2f(l2d * jl);
  }

  floatx4 oacc[4];
#pragma unroll
  for (int i = 0; i < 4; ++i) oacc[i] = (floatx4){0.f, 0.f, 0.f, 0.f};
  float zacc[4] = {0.f, 0.f, 0.f, 0.f};

  for (int j0 = 0; j0 < TT; j0 += 128) {
    const int gap = i0 - j0;
    int mind = 0;
    if (gap >= 128) mind = gap - 127;
    else if (gap <= -64) mind = -gap - 63;
    if (l2d * (float)mind < -40.f) continue;  // max tile weight < 2^-40: negligible

    __syncthreads();  // previous PV reads done before restaging
#pragma unroll
    for (int r2 = 0; r2 < 4; ++r2) {
      int c = tid + r2 * 256;
      int row = c >> 3, c16 = (c & 7) * 8;
      *(uint4*)(&Ks[row * 72 + c16]) = *(const uint4*)(Kb + (size_t)(j0 + row) * HD + c16);
    }
#pragma unroll
    for (int r2 = 0; r2 < 4; ++r2) {
      int c = tid + r2 * 256;
      int row = c >> 4, c16 = (c & 15) * 8;
      *(uint4*)(&Vts[row * 136 + c16]) = *(const uint4*)(Vb + (size_t)row * TT + j0 + c16);
    }
    __syncthreads();

    const float wS = exp2f(l2d * (float)gap);    // d^(i0-j0)   (used when i>=j)
    const float wSb = exp2f(-l2d * (float)gap);  // d^(j0-i0)   (used when j>i)

#pragma unroll
    for (int nb = 0; nb < 8; ++nb) {
      floatx4 sacc = (floatx4){0.f, 0.f, 0.f, 0.f};
#pragma unroll
      for (int kb = 0; kb < 2; ++kb) {
        bf16x8 bk = frag16(&Ks[(nb * 16 + ln) * 72 + kb * 32 + quad * 8]);
        sacc = mfma_bf16(qa[kb], bk, sacc);
      }
#pragma unroll
      for (int r = 0; r < 4; ++r) {
        int il = wid * 16 + quad * 4 + r;
        int jl = nb * 16 + ln;
        int sd = gap + il - jl;  // i - j
        float w;
        if (fast)
          w = (sd >= 0) ? (wS * rf[r]) * cf[nb] : (wSb * rfi[r]) * cfi[nb];
        else
          w = exp2f(l2d * fabsf((float)sd));
        float sv = sacc[r] * w;
        zacc[r] += sv;
        Ss[(size_t)(wid * 16 + quad * 4 + r) * 136 + nb * 16 + ln] = f2bf(sv);
      }
    }
    __syncthreads();  // S visible (also orders within-wave write->read)

    bf16x8 af[4];
#pragma unroll
    for (int kb = 0; kb < 4; ++kb)
      af[kb] = frag16(&Ss[(size_t)(wid * 16 + ln) * 136 + kb * 32 + quad * 8]);
#pragma unroll
    for (int n2 = 0; n2 < 4; ++n2) {
#pragma unroll
      for (int kb = 0; kb < 4; ++kb) {
        bf16x8 bv = frag16(&Vts[(size_t)(n2 * 16 + ln) * 136 + kb * 32 + quad * 8]);
        oacc[n2] = mfma_bf16(af[kb], bv, oacc[n2]);
      }
    }
  }

  // row-sum denominator: reduce zacc across the 16 lanes of each quad
  float rz[4];
#pragma unroll
  for (int r = 0; r < 4; ++r) {
    float z = zacc[r];
    z += __shfl_xor(z, 1);
    z += __shfl_xor(z, 2);
    z += __shfl_xor(z, 4);
    z += __shfl_xor(z, 8);
    rz[r] = 1.f / fmaxf(z, 1e-6f);
  }

#pragma unroll
  for (int n2 = 0; n2 < 4; ++n2)
#pragma unroll
    for (int r = 0; r < 4; ++r) {
      int i = i0 + wid * 16 + quad * 4 + r;
      int col = h * 64 + n2 * 16 + ln;
      attn_out[(size_t)(b * TT + i) * DD + col] = f2bf(oacc[n2][r] * rz[r]);
    }
}

extern "C" void kernel_launch(void* const* d_in, const int* in_sizes, int n_in,
                              void* d_out, int out_size, void* d_ws, size_t ws_size,
                              hipStream_t stream) {
  const float* x = (const float*)d_in[0];
  const unsigned char* msk = (const unsigned char*)d_in[1];
  const float* wq = (const float*)d_in[2];
  const float* wk = (const float*)d_in[3];
  const float* wv = (const float*)d_in[4];
  const float* wo = (const float*)d_in[5];
  const float* bo = (const float*)d_in[6];
  const float* g1 = (const float*)d_in[7];
  const float* b1 = (const float*)d_in[8];
  const float* g2 = (const float*)d_in[9];
  const float* b2 = (const float*)d_in[10];
  const float* w1 = (const float*)d_in[11];
  const float* bf1 = (const float*)d_in[12];
  const float* w2 = (const float*)d_in[13];
  const float* bf2 = (const float*)d_in[14];
  const float* dlg = (const float*)d_in[15];
  float* out = (float*)d_out;

  char* p = (char*)d_ws;
  size_t off = 0;
  auto carve = [&](size_t bytes) {
    char* q = p + off;
    off += (bytes + 255) & ~(size_t)255;
    return q;
  };
  unsigned short* xn = (unsigned short*)carve((size_t)M4 * DD * 2);
  unsigned short* wqkvT = (unsigned short*)carve((size_t)1536 * DD * 2);
  unsigned short* woT = (unsigned short*)carve((size_t)DD * DD * 2);
  unsigned short* w1T = (unsigned short*)carve((size_t)FF_ * DD * 2);
  unsigned short* w2T = (unsigned short*)carve((size_t)DD * FF_ * 2);
  unsigned short* Qb = (unsigned short*)carve((size_t)16 * TT * HD * 2);
  unsigned short* Kb = (unsigned short*)carve((size_t)16 * TT * HD * 2);
  unsigned short* Vtb = (unsigned short*)carve((size_t)16 * HD * TT * 2);
  unsigned short* attn = (unsigned short*)carve((size_t)M4 * DD * 2);
  float* x2 = (float*)carve((size_t)M4 * DD * 4);
  unsigned short* xn2 = (unsigned short*)carve((size_t)M4 * DD * 2);
  unsigned short* ffh = (unsigned short*)carve((size_t)M4 * FF_ * 2);

  dim3 tb(32, 8);
  transpose_bf16<<<dim3(16, 16), tb, 0, stream>>>(wq, wqkvT, DD, DD);
  transpose_bf16<<<dim3(16, 16), tb, 0, stream>>>(wk, wqkvT + 512 * 512, DD, DD);
  transpose_bf16<<<dim3(16, 16), tb, 0, stream>>>(wv, wqkvT + 2 * 512 * 512, DD, DD);
  transpose_bf16<<<dim3(16, 16), tb, 0, stream>>>(wo, woT, DD, DD);
  transpose_bf16<<<dim3(64, 16), tb, 0, stream>>>(w1, w1T, DD, FF_);
  transpose_bf16<<<dim3(16, 64), tb, 0, stream>>>(w2, w2T, FF_, DD);

  ln_kernel<<<M4, 128, 0, stream>>>(x, g1, b1, xn);

  // QKV: M=4096, N=1536, K=512 — 128x128 tiles, 384 blocks
  gemm_bt<128, 128, 0><<<dim3(1536 / 128, M4 / 128), 256, 0, stream>>>(
      xn, wqkvT, 1536, DD, nullptr, nullptr, nullptr, Qb, Kb, Vtb, msk);

  attn_kernel<<<dim3(TT / 64, 16), 256, 0, stream>>>(Qb, Kb, Vtb, dlg, attn);

  // out-proj: M=4096, N=512, K=512 — 64x64 tiles, 512 blocks (2/CU)
  gemm_bt<64, 64, 1><<<dim3(DD / 64, M4 / 64), 256, 0, stream>>>(
      attn, woT, DD, DD, bo, x, x2, nullptr, nullptr, nullptr, nullptr);

  ln_kernel<<<M4, 128, 0, stream>>>(x2, g2, b2, xn2);

  // FFN1: M=4096, N=2048, K=512 — 128x128 tiles, 512 blocks
  gemm_bt<128, 128, 2><<<dim3(FF_ / 128, M4 / 128), 256, 0, stream>>>(
      xn2, w1T, FF_, DD, bf1, nullptr, nullptr, ffh, nullptr, nullptr, nullptr);

  // FFN2: M=4096, N=512, K=2048 — 64x64 tiles, 512 blocks (2/CU)
  gemm_bt<64, 64, 1><<<dim3(DD / 64, M4 / 64), 256, 0, stream>>>(
      ffh, w2T, DD, FF_, bf2, x2, out, nullptr, nullptr, nullptr, nullptr);
}